// Round 1
// baseline (171.023 us; speedup 1.0000x reference)
//
#include <hip/hip_runtime.h>
#include <math.h>

#pragma clang fp contract(off)

#define NA      896
#define MAXDET  256
#define NBATCH  512

// One wave (64 lanes) per batch element. Candidates (score >= 0.75) are
// compacted in anchor order into LDS as decoded 17-float rows. The NMS scan
// runs entirely on one wave: packed-u64 shfl argmax, ballot-based cluster
// count, register-resident "remaining" bitmask (bit j of lane L = candidate
// L + 64*j), weighted reduction only when a cluster has n > 1.
__global__ __launch_bounds__(64, 1) void blazeface_nms(
    const float* __restrict__ raw_box,    // [512][896][16]
    const float* __restrict__ raw_score,  // [512][896]
    const float* __restrict__ anchors,    // [896][4]
    float* __restrict__ out,              // [512][256][17]
    float* __restrict__ flags)            // [512][256]
{
    __shared__ float det[NA][17];
    __shared__ int   cand_a[NA];

    const int b    = blockIdx.x;
    const int lane = threadIdx.x;

    // ---- Phase 1: scores + stable compaction (anchor-ascending order) ----
    int C = 0;
    const float* sc_base = raw_score + (size_t)b * NA;
    #pragma unroll
    for (int c = 0; c < NA / 64; ++c) {
        int a = c * 64 + lane;
        float x = sc_base[a];
        x = fminf(fmaxf(x, -100.0f), 100.0f);
        float s = 1.0f / (1.0f + expf(-x));
        bool v = (s >= 0.75f);
        unsigned long long bal = __ballot(v);
        if (v) {
            int slot = C + (int)__popcll(bal & ((1ull << lane) - 1ull));
            cand_a[slot]  = a;
            det[slot][16] = s;
        }
        C += (int)__popcll(bal);
    }
    __syncthreads();

    // ---- Phase 2: decode candidate rows into LDS ----
    for (int k = lane; k < C; k += 64) {
        int a = cand_a[k];
        const float4 an = ((const float4*)anchors)[a];
        const float4* rb = (const float4*)(raw_box + ((size_t)b * NA + a) * 16);
        float4 r0 = rb[0], r1 = rb[1], r2 = rb[2], r3 = rb[3];
        float ax = an.x, ay = an.y, aw = an.z, ah = an.w;
        float xc = r0.x / 128.0f * aw + ax;
        float yc = r0.y / 128.0f * ah + ay;
        float w  = r0.z / 128.0f * aw;
        float h  = r0.w / 128.0f * ah;
        det[k][0] = yc - h * 0.5f;
        det[k][1] = xc - w * 0.5f;
        det[k][2] = yc + h * 0.5f;
        det[k][3] = xc + w * 0.5f;
        float kp[12] = {r1.x, r1.y, r1.z, r1.w,
                        r2.x, r2.y, r2.z, r2.w,
                        r3.x, r3.y, r3.z, r3.w};
        #pragma unroll
        for (int t = 0; t < 6; ++t) {
            det[k][4 + 2 * t] = kp[2 * t]     / 128.0f * aw + ax;
            det[k][5 + 2 * t] = kp[2 * t + 1] / 128.0f * ah + ay;
        }
    }
    __syncthreads();

    const int nj = (C + 63) >> 6;
    unsigned int rem = 0;
    for (int j = 0; j < nj; ++j)
        if (lane + (j << 6) < C) rem |= (1u << j);

    float* out_b = out   + (size_t)b * MAXDET * 17;
    float* flg_b = flags + (size_t)b * MAXDET;

    // ---- Phase 3: sequential NMS scan ----
    int step = 0;
    for (; step < MAXDET; ++step) {
        // argmax over remaining, first-index tiebreak, via packed u64 key
        unsigned long long best = 0;
        for (int j = 0; j < nj; ++j) {
            if (rem & (1u << j)) {
                int k = lane + (j << 6);
                unsigned long long key =
                    ((unsigned long long)__float_as_uint(det[k][16]) << 10) |
                    (unsigned long long)(1023 - k);
                if (key > best) best = key;
            }
        }
        #pragma unroll
        for (int off = 32; off; off >>= 1) {
            unsigned long long o = __shfl_xor(best, off);
            if (o > best) best = o;
        }
        if (best == 0) break;  // any_left == False: zeros from here on
        int idx = 1023 - (int)(best & 1023ull);

        float bx0 = det[idx][0], bx1 = det[idx][1];
        float bx2 = det[idx][2], bx3 = det[idx][3];
        float areaA = (bx2 - bx0) * (bx3 - bx1);

        // IoU vs remaining candidates; overlap bitmask
        unsigned int ov = 0;
        for (int j = 0; j < nj; ++j) {
            if (rem & (1u << j)) {
                int k = lane + (j << 6);
                float c0 = det[k][0], c1 = det[k][1];
                float c2 = det[k][2], c3 = det[k][3];
                float i0 = fmaxf(bx0, c0);
                float i1 = fmaxf(bx1, c1);
                float i2 = fminf(bx2, c2);
                float i3 = fminf(bx3, c3);
                float inter = (i2 - i0) * (i3 - i1);
                float areaB = (c2 - c0) * (c3 - c1);
                float uni   = areaA + areaB - inter;
                float q     = inter / uni;   // NaN compares false, like jnp
                if (q > 0.3f) ov |= (1u << j);
            }
        }
        rem &= ~ov;

        // cluster size n (uniform across lanes) via ballots
        int n = 0;
        for (int j = 0; j < nj; ++j) {
            unsigned long long bj = __ballot((ov >> j) & 1u);
            n += (int)__popcll(bj);
        }

        if (n <= 1) {
            // exact copy of det[idx] (reference: wdet = det[idx])
            if (lane < 17) out_b[step * 17 + lane] = det[idx][lane];
            if (lane == 17) flg_b[step] = 1.0f;
        } else {
            float tot = 0.0f;
            float wc[16];
            #pragma unroll
            for (int c = 0; c < 16; ++c) wc[c] = 0.0f;
            for (int j = 0; j < nj; ++j) {
                if (ov & (1u << j)) {
                    int k = lane + (j << 6);
                    float s = det[k][16];
                    tot += s;
                    #pragma unroll
                    for (int c = 0; c < 16; ++c) wc[c] += det[k][c] * s;
                }
            }
            #pragma unroll
            for (int off = 32; off; off >>= 1) {
                tot += __shfl_xor(tot, off);
                #pragma unroll
                for (int c = 0; c < 16; ++c) wc[c] += __shfl_xor(wc[c], off);
            }
            if (lane == 0) {
                float safe = (tot > 0.0f) ? tot : 1.0f;
                #pragma unroll
                for (int c = 0; c < 16; ++c) out_b[step * 17 + c] = wc[c] / safe;
                out_b[step * 17 + 16] = tot / (float)n;
                flg_b[step] = 1.0f;
            }
        }
    }

    // ---- Phase 4: zero-fill the exhausted tail (harness poisons d_out) ----
    for (int t = step * 17 + lane; t < MAXDET * 17; t += 64) out_b[t] = 0.0f;
    for (int t = step + lane;      t < MAXDET;      t += 64) flg_b[t] = 0.0f;
}

extern "C" void kernel_launch(void* const* d_in, const int* in_sizes, int n_in,
                              void* d_out, int out_size, void* d_ws, size_t ws_size,
                              hipStream_t stream) {
    const float* raw_box   = (const float*)d_in[0];
    const float* raw_score = (const float*)d_in[1];
    const float* anchors   = (const float*)d_in[2];
    float* out   = (float*)d_out;
    float* flags = out + (size_t)NBATCH * MAXDET * 17;
    blazeface_nms<<<NBATCH, 64, 0, stream>>>(raw_box, raw_score, anchors, out, flags);
}

// Round 2
// 105.512 us; speedup vs baseline: 1.6209x; 1.6209x over previous
//
#include <hip/hip_runtime.h>
#include <math.h>

#pragma clang fp contract(off)

#define NA      896
#define MAXDET  256
#define NBATCH  512
#define NREG    3
#define CAP     (NREG * 64)   // 192 register-resident candidates per batch

__device__ __forceinline__ float rlane(float v, int l) {
    return __int_as_float(__builtin_amdgcn_readlane(__float_as_int(v), l));
}

// ---------------- fast path: C <= 192 candidates ----------------
// One wave per batch. Candidates compacted, decoded, then SORTED by
// (score desc, anchor asc) via rank-by-count. Rows live in registers
// (3 sets x 17 floats / lane). Per-step pick = ballot + ffs (no shfl
// chain, no LDS on the critical path).
__global__ __launch_bounds__(64, 1) void nms_fast(
    const float* __restrict__ raw_box,
    const float* __restrict__ raw_score,
    const float* __restrict__ anchors,
    float* __restrict__ out,
    float* __restrict__ flags)
{
    __shared__ float det[CAP][17];
    __shared__ unsigned long long keys[CAP];
    __shared__ int cand_a[CAP];
    __shared__ int srt_from[CAP];

    const int b    = blockIdx.x;
    const int lane = threadIdx.x;

    // ---- Phase 1: scores + stable compaction ----
    int C = 0;
    const float* sc_base = raw_score + (size_t)b * NA;
    #pragma unroll
    for (int c = 0; c < NA / 64; ++c) {
        int a = c * 64 + lane;
        float x = sc_base[a];
        x = fminf(fmaxf(x, -100.0f), 100.0f);
        float s = 1.0f / (1.0f + expf(-x));
        bool v = (s >= 0.75f);
        unsigned long long bal = __ballot(v);
        if (v) {
            int slot = C + (int)__popcll(bal & ((1ull << lane) - 1ull));
            if (slot < CAP) {
                cand_a[slot]  = a;
                det[slot][16] = s;
                keys[slot] = ((unsigned long long)__float_as_uint(s) << 8)
                           | (unsigned long long)(255 - slot);
            }
        }
        C += (int)__popcll(bal);
    }
    if (C > CAP) return;   // fallback kernel handles this block
    __syncthreads();

    // ---- Phase 2: decode candidate rows into LDS ----
    for (int k = lane; k < C; k += 64) {
        int a = cand_a[k];
        const float4 an = ((const float4*)anchors)[a];
        const float4* rb = (const float4*)(raw_box + ((size_t)b * NA + a) * 16);
        float4 r0 = rb[0], r1 = rb[1], r2 = rb[2], r3 = rb[3];
        float ax = an.x, ay = an.y, aw = an.z, ah = an.w;
        float xc = r0.x / 128.0f * aw + ax;
        float yc = r0.y / 128.0f * ah + ay;
        float w  = r0.z / 128.0f * aw;
        float h  = r0.w / 128.0f * ah;
        det[k][0] = yc - h * 0.5f;
        det[k][1] = xc - w * 0.5f;
        det[k][2] = yc + h * 0.5f;
        det[k][3] = xc + w * 0.5f;
        float kp[12] = {r1.x, r1.y, r1.z, r1.w,
                        r2.x, r2.y, r2.z, r2.w,
                        r3.x, r3.y, r3.z, r3.w};
        #pragma unroll
        for (int t = 0; t < 6; ++t) {
            det[k][4 + 2 * t] = kp[2 * t]     / 128.0f * aw + ax;
            det[k][5 + 2 * t] = kp[2 * t + 1] / 128.0f * ah + ay;
        }
    }
    __syncthreads();

    // ---- Phase 3: rank-by-count sort (unique keys) ----
    const int r0i = lane, r1i = lane + 64, r2i = lane + 128;
    unsigned long long k0 = 0, k1 = 0, k2 = 0;
    if (r0i < C) k0 = keys[r0i];
    if (r1i < C) k1 = keys[r1i];
    if (r2i < C) k2 = keys[r2i];
    int q0 = 0, q1 = 0, q2 = 0;
    #pragma unroll 4
    for (int i = 0; i < C; ++i) {
        unsigned long long ki = keys[i];
        q0 += (ki > k0); q1 += (ki > k1); q2 += (ki > k2);
    }
    if (r0i < C) srt_from[q0] = r0i;
    if (r1i < C) srt_from[q1] = r1i;
    if (r2i < C) srt_from[q2] = r2i;
    __syncthreads();

    // ---- Phase 4: load sorted rows into registers ----
    float R0[17], R1[17], R2[17];
    #pragma unroll
    for (int c = 0; c < 17; ++c) { R0[c] = 0.0f; R1[c] = 0.0f; R2[c] = 0.0f; }
    if (r0i < C) { int k = srt_from[r0i];
        #pragma unroll
        for (int c = 0; c < 17; ++c) R0[c] = det[k][c]; }
    if (r1i < C) { int k = srt_from[r1i];
        #pragma unroll
        for (int c = 0; c < 17; ++c) R1[c] = det[k][c]; }
    if (r2i < C) { int k = srt_from[r2i];
        #pragma unroll
        for (int c = 0; c < 17; ++c) R2[c] = det[k][c]; }

    unsigned int rem = 0;
    if (r0i < C) rem |= 1u;
    if (r1i < C) rem |= 2u;
    if (r2i < C) rem |= 4u;

    float* out_b = out   + (size_t)b * MAXDET * 17;
    float* flg_b = flags + (size_t)b * MAXDET;

    // ---- Phase 5: sequential NMS scan, register-resident ----
    int step = 0;
    for (; step < MAXDET; ++step) {
        unsigned long long b0 = __ballot((rem & 1u) != 0);
        unsigned long long b1 = __ballot((rem & 2u) != 0);
        unsigned long long b2 = __ballot((rem & 4u) != 0);
        int sl, sj;
        if      (b0) { sl = __ffsll(b0) - 1; sj = 0; }
        else if (b1) { sl = __ffsll(b1) - 1; sj = 1; }
        else if (b2) { sl = __ffsll(b2) - 1; sj = 2; }
        else break;   // nothing remaining: zeros from here on

        float bx0, bx1, bx2, bx3;
        if (sj == 0) { bx0 = rlane(R0[0], sl); bx1 = rlane(R0[1], sl);
                       bx2 = rlane(R0[2], sl); bx3 = rlane(R0[3], sl); }
        else if (sj == 1) { bx0 = rlane(R1[0], sl); bx1 = rlane(R1[1], sl);
                            bx2 = rlane(R1[2], sl); bx3 = rlane(R1[3], sl); }
        else { bx0 = rlane(R2[0], sl); bx1 = rlane(R2[1], sl);
               bx2 = rlane(R2[2], sl); bx3 = rlane(R2[3], sl); }
        float areaA = (bx2 - bx0) * (bx3 - bx1);

        unsigned int ov = 0;
        {
            float i0 = fmaxf(bx0, R0[0]), i1 = fmaxf(bx1, R0[1]);
            float i2 = fminf(bx2, R0[2]), i3 = fminf(bx3, R0[3]);
            float inter = (i2 - i0) * (i3 - i1);
            float areaB = (R0[2] - R0[0]) * (R0[3] - R0[1]);
            float q = inter / (areaA + areaB - inter);
            if ((rem & 1u) && (q > 0.3f)) ov |= 1u;
        }
        {
            float i0 = fmaxf(bx0, R1[0]), i1 = fmaxf(bx1, R1[1]);
            float i2 = fminf(bx2, R1[2]), i3 = fminf(bx3, R1[3]);
            float inter = (i2 - i0) * (i3 - i1);
            float areaB = (R1[2] - R1[0]) * (R1[3] - R1[1]);
            float q = inter / (areaA + areaB - inter);
            if ((rem & 2u) && (q > 0.3f)) ov |= 2u;
        }
        {
            float i0 = fmaxf(bx0, R2[0]), i1 = fmaxf(bx1, R2[1]);
            float i2 = fminf(bx2, R2[2]), i3 = fminf(bx3, R2[3]);
            float inter = (i2 - i0) * (i3 - i1);
            float areaB = (R2[2] - R2[0]) * (R2[3] - R2[1]);
            float q = inter / (areaA + areaB - inter);
            if ((rem & 4u) && (q > 0.3f)) ov |= 4u;
        }
        rem &= ~ov;

        int n = (int)__popcll(__ballot((ov & 1u) != 0))
              + (int)__popcll(__ballot((ov & 2u) != 0))
              + (int)__popcll(__ballot((ov & 4u) != 0));

        if (n <= 1) {
            // exact copy of det[idx]; owner lane fires the stores
            if (sj == 0) { if (lane == sl) {
                #pragma unroll
                for (int c = 0; c < 17; ++c) out_b[step * 17 + c] = R0[c];
                flg_b[step] = 1.0f; } }
            else if (sj == 1) { if (lane == sl) {
                #pragma unroll
                for (int c = 0; c < 17; ++c) out_b[step * 17 + c] = R1[c];
                flg_b[step] = 1.0f; } }
            else { if (lane == sl) {
                #pragma unroll
                for (int c = 0; c < 17; ++c) out_b[step * 17 + c] = R2[c];
                flg_b[step] = 1.0f; } }
        } else {
            float tot = 0.0f, wc[16];
            #pragma unroll
            for (int c = 0; c < 16; ++c) wc[c] = 0.0f;
            { float m = (ov & 1u) ? R0[16] : 0.0f; tot += m;
              #pragma unroll
              for (int c = 0; c < 16; ++c) wc[c] += R0[c] * m; }
            { float m = (ov & 2u) ? R1[16] : 0.0f; tot += m;
              #pragma unroll
              for (int c = 0; c < 16; ++c) wc[c] += R1[c] * m; }
            { float m = (ov & 4u) ? R2[16] : 0.0f; tot += m;
              #pragma unroll
              for (int c = 0; c < 16; ++c) wc[c] += R2[c] * m; }
            #pragma unroll
            for (int off = 32; off; off >>= 1) {
                tot += __shfl_xor(tot, off);
                #pragma unroll
                for (int c = 0; c < 16; ++c) wc[c] += __shfl_xor(wc[c], off);
            }
            if (lane == 0) {
                float safe = (tot > 0.0f) ? tot : 1.0f;
                #pragma unroll
                for (int c = 0; c < 16; ++c) out_b[step * 17 + c] = wc[c] / safe;
                out_b[step * 17 + 16] = tot / (float)n;
                flg_b[step] = 1.0f;
            }
        }
    }

    // ---- Phase 6: zero-fill exhausted tail ----
    for (int t = step * 17 + lane; t < MAXDET * 17; t += 64) out_b[t] = 0.0f;
    for (int t = step + lane;      t < MAXDET;      t += 64) flg_b[t] = 0.0f;
}

// ---------------- fallback: C > 192 (never on this data; kept for correctness) ----------------
__global__ __launch_bounds__(64, 1) void nms_fallback(
    const float* __restrict__ raw_box,
    const float* __restrict__ raw_score,
    const float* __restrict__ anchors,
    float* __restrict__ out,
    float* __restrict__ flags)
{
    __shared__ float det[NA][17];
    __shared__ int   cand_a[NA];

    const int b    = blockIdx.x;
    const int lane = threadIdx.x;

    int C = 0;
    const float* sc_base = raw_score + (size_t)b * NA;
    #pragma unroll
    for (int c = 0; c < NA / 64; ++c) {
        int a = c * 64 + lane;
        float x = sc_base[a];
        x = fminf(fmaxf(x, -100.0f), 100.0f);
        float s = 1.0f / (1.0f + expf(-x));
        bool v = (s >= 0.75f);
        unsigned long long bal = __ballot(v);
        if (v) {
            int slot = C + (int)__popcll(bal & ((1ull << lane) - 1ull));
            cand_a[slot]  = a;
            det[slot][16] = s;
        }
        C += (int)__popcll(bal);
    }
    if (C <= CAP) return;   // fast kernel owns this block
    __syncthreads();

    for (int k = lane; k < C; k += 64) {
        int a = cand_a[k];
        const float4 an = ((const float4*)anchors)[a];
        const float4* rb = (const float4*)(raw_box + ((size_t)b * NA + a) * 16);
        float4 r0 = rb[0], r1 = rb[1], r2 = rb[2], r3 = rb[3];
        float ax = an.x, ay = an.y, aw = an.z, ah = an.w;
        float xc = r0.x / 128.0f * aw + ax;
        float yc = r0.y / 128.0f * ah + ay;
        float w  = r0.z / 128.0f * aw;
        float h  = r0.w / 128.0f * ah;
        det[k][0] = yc - h * 0.5f;
        det[k][1] = xc - w * 0.5f;
        det[k][2] = yc + h * 0.5f;
        det[k][3] = xc + w * 0.5f;
        float kp[12] = {r1.x, r1.y, r1.z, r1.w,
                        r2.x, r2.y, r2.z, r2.w,
                        r3.x, r3.y, r3.z, r3.w};
        #pragma unroll
        for (int t = 0; t < 6; ++t) {
            det[k][4 + 2 * t] = kp[2 * t]     / 128.0f * aw + ax;
            det[k][5 + 2 * t] = kp[2 * t + 1] / 128.0f * ah + ay;
        }
    }
    __syncthreads();

    const int nj = (C + 63) >> 6;
    unsigned int rem = 0;
    for (int j = 0; j < nj; ++j)
        if (lane + (j << 6) < C) rem |= (1u << j);

    float* out_b = out   + (size_t)b * MAXDET * 17;
    float* flg_b = flags + (size_t)b * MAXDET;

    int step = 0;
    for (; step < MAXDET; ++step) {
        unsigned long long best = 0;
        for (int j = 0; j < nj; ++j) {
            if (rem & (1u << j)) {
                int k = lane + (j << 6);
                unsigned long long key =
                    ((unsigned long long)__float_as_uint(det[k][16]) << 10) |
                    (unsigned long long)(1023 - k);
                if (key > best) best = key;
            }
        }
        #pragma unroll
        for (int off = 32; off; off >>= 1) {
            unsigned long long o = __shfl_xor(best, off);
            if (o > best) best = o;
        }
        if (best == 0) break;
        int idx = 1023 - (int)(best & 1023ull);

        float bx0 = det[idx][0], bx1 = det[idx][1];
        float bx2 = det[idx][2], bx3 = det[idx][3];
        float areaA = (bx2 - bx0) * (bx3 - bx1);

        unsigned int ov = 0;
        for (int j = 0; j < nj; ++j) {
            if (rem & (1u << j)) {
                int k = lane + (j << 6);
                float c0 = det[k][0], c1 = det[k][1];
                float c2 = det[k][2], c3 = det[k][3];
                float i0 = fmaxf(bx0, c0);
                float i1 = fmaxf(bx1, c1);
                float i2 = fminf(bx2, c2);
                float i3 = fminf(bx3, c3);
                float inter = (i2 - i0) * (i3 - i1);
                float areaB = (c2 - c0) * (c3 - c1);
                float uni   = areaA + areaB - inter;
                float q     = inter / uni;
                if (q > 0.3f) ov |= (1u << j);
            }
        }
        rem &= ~ov;

        int n = 0;
        for (int j = 0; j < nj; ++j) {
            unsigned long long bj = __ballot((ov >> j) & 1u);
            n += (int)__popcll(bj);
        }

        if (n <= 1) {
            if (lane < 17) out_b[step * 17 + lane] = det[idx][lane];
            if (lane == 17) flg_b[step] = 1.0f;
        } else {
            float tot = 0.0f;
            float wc[16];
            #pragma unroll
            for (int c = 0; c < 16; ++c) wc[c] = 0.0f;
            for (int j = 0; j < nj; ++j) {
                if (ov & (1u << j)) {
                    int k = lane + (j << 6);
                    float s = det[k][16];
                    tot += s;
                    #pragma unroll
                    for (int c = 0; c < 16; ++c) wc[c] += det[k][c] * s;
                }
            }
            #pragma unroll
            for (int off = 32; off; off >>= 1) {
                tot += __shfl_xor(tot, off);
                #pragma unroll
                for (int c = 0; c < 16; ++c) wc[c] += __shfl_xor(wc[c], off);
            }
            if (lane == 0) {
                float safe = (tot > 0.0f) ? tot : 1.0f;
                #pragma unroll
                for (int c = 0; c < 16; ++c) out_b[step * 17 + c] = wc[c] / safe;
                out_b[step * 17 + 16] = tot / (float)n;
                flg_b[step] = 1.0f;
            }
        }
    }

    for (int t = step * 17 + lane; t < MAXDET * 17; t += 64) out_b[t] = 0.0f;
    for (int t = step + lane;      t < MAXDET;      t += 64) flg_b[t] = 0.0f;
}

extern "C" void kernel_launch(void* const* d_in, const int* in_sizes, int n_in,
                              void* d_out, int out_size, void* d_ws, size_t ws_size,
                              hipStream_t stream) {
    const float* raw_box   = (const float*)d_in[0];
    const float* raw_score = (const float*)d_in[1];
    const float* anchors   = (const float*)d_in[2];
    float* out   = (float*)d_out;
    float* flags = out + (size_t)NBATCH * MAXDET * 17;
    nms_fast    <<<NBATCH, 64, 0, stream>>>(raw_box, raw_score, anchors, out, flags);
    nms_fallback<<<NBATCH, 64, 0, stream>>>(raw_box, raw_score, anchors, out, flags);
}

// Round 3
// 67.547 us; speedup vs baseline: 2.5319x; 1.5621x over previous
//
#include <hip/hip_runtime.h>
#include <math.h>

#pragma clang fp contract(off)

#define NA      896
#define MAXDET  256
#define NBATCH  512
#define CAP     192

typedef unsigned long long u64;
typedef unsigned int u32;

__device__ __forceinline__ u64 rl64(u64 v, int l) {
    u32 lo = __builtin_amdgcn_readlane((u32)v, l);
    u32 hi = __builtin_amdgcn_readlane((u32)(v >> 32), l);
    return ((u64)hi << 32) | (u64)lo;
}

// IoU>0.3 bit vs broadcast box bk/ak. Operand order matches reference with
// the OWN candidate as the picked box: union = area_own + area_k - inter.
#define IOU_BIT(BX, BY, BZ, BW, AR, MASK)                              \
    {                                                                  \
        float i0 = fmaxf((BX), bk.x), i1 = fmaxf((BY), bk.y);          \
        float i2 = fminf((BZ), bk.z), i3 = fminf((BW), bk.w);          \
        float inter = (i2 - i0) * (i3 - i1);                           \
        float q = inter / ((AR) + ak - inter);  /* NaN -> no bit */    \
        if (q > 0.3f) (MASK) |= bit;                                   \
    }

#define MATRIX_WORD(M0, M1, M2, KBASE)                                 \
    {                                                                  \
        int ke = C - (KBASE); if (ke > 64) ke = 64;                    \
        u64 bit = 1ull;                                                \
        _Pragma("unroll 2")                                            \
        for (int k = 0; k < ke; ++k, bit <<= 1) {                      \
            float4 bk = sbox[(KBASE) + k];                             \
            float ak = (bk.z - bk.x) * (bk.w - bk.y);                  \
            IOU_BIT(b00, b01, b02, b03, a0, M0)                        \
            IOU_BIT(b10, b11, b12, b13, a1, M1)                        \
            IOU_BIT(b20, b21, b22, b23, a2, M2)                        \
        }                                                              \
    }

#define ACCUM_WORD(MASK, BASE)                                         \
    {                                                                  \
        u64 m_ = (MASK);                                               \
        while (m_) {                                                   \
            int k_ = __builtin_ctzll(m_) + (BASE);                     \
            m_ &= m_ - 1;                                              \
            float sc_ = det[k_][16];                                   \
            tot += sc_;                                                \
            _Pragma("unroll")                                          \
            for (int c = 0; c < 16; ++c) wc[c] += det[k_][c] * sc_;    \
        }                                                              \
    }

// ---------------- fast path: C <= 192 candidates, one wave per batch -------
__global__ __launch_bounds__(64, 1) void nms_fast(
    const float* __restrict__ raw_box,
    const float* __restrict__ raw_score,
    const float* __restrict__ anchors,
    float* __restrict__ out,
    float* __restrict__ flags,
    int* __restrict__ ws, int use_ws)
{
    __shared__ float  det[CAP][17];
    __shared__ float4 sbox[CAP];
    __shared__ u64    keys[CAP];
    __shared__ int    slot_a[CAP];
    __shared__ float  slot_s[CAP];
    __shared__ int    srt_a[CAP];
    __shared__ u64    cl0[MAXDET], cl1[MAXDET], cl2[MAXDET];
    __shared__ u32    pk[MAXDET];

    const int b    = blockIdx.x;
    const int lane = threadIdx.x;

    // ---- Phase 1: scores + stable compaction (anchor order) ----
    int C = 0;
    const float* sc_base = raw_score + (size_t)b * NA;
    #pragma unroll
    for (int c = 0; c < NA / 64; ++c) {
        int a = c * 64 + lane;
        float x = sc_base[a];
        x = fminf(fmaxf(x, -100.0f), 100.0f);
        float s = 1.0f / (1.0f + expf(-x));
        bool v = (s >= 0.75f);
        u64 bal = __ballot(v);
        if (v) {
            int slot = C + (int)__popcll(bal & ((1ull << lane) - 1ull));
            if (slot < CAP) {
                keys[slot]   = ((u64)__float_as_uint(s) << 8) | (u64)(255 - slot);
                slot_a[slot] = a;
                slot_s[slot] = s;
            }
        }
        C += (int)__popcll(bal);
    }
    if (use_ws && lane == 0) ws[b] = C;
    if (C > CAP) return;   // fallback kernel owns this block
    __syncthreads();

    // ---- Phase 2: rank-by-count sort (keys unique) ----
    {
        u64 k0 = 0, k1 = 0, k2 = 0;
        if (lane < C)        k0 = keys[lane];
        if (lane + 64 < C)   k1 = keys[lane + 64];
        if (lane + 128 < C)  k2 = keys[lane + 128];
        int q0 = 0, q1 = 0, q2 = 0;
        #pragma unroll 4
        for (int i = 0; i < C; ++i) {
            u64 ki = keys[i];
            q0 += (ki > k0); q1 += (ki > k1); q2 += (ki > k2);
        }
        if (lane < C)       { srt_a[q0] = slot_a[lane];       det[q0][16] = slot_s[lane]; }
        if (lane + 64 < C)  { srt_a[q1] = slot_a[lane + 64];  det[q1][16] = slot_s[lane + 64]; }
        if (lane + 128 < C) { srt_a[q2] = slot_a[lane + 128]; det[q2][16] = slot_s[lane + 128]; }
    }
    __syncthreads();

    // ---- Phase 3: decode into sorted LDS rows ----
    for (int k = lane; k < C; k += 64) {
        int a = srt_a[k];
        const float4 an = ((const float4*)anchors)[a];
        const float4* rb = (const float4*)(raw_box + ((size_t)b * NA + a) * 16);
        float4 r0 = rb[0], r1 = rb[1], r2 = rb[2], r3 = rb[3];
        float ax = an.x, ay = an.y, aw = an.z, ah = an.w;
        float xc = r0.x / 128.0f * aw + ax;
        float yc = r0.y / 128.0f * ah + ay;
        float w  = r0.z / 128.0f * aw;
        float h  = r0.w / 128.0f * ah;
        float d0 = yc - h * 0.5f, d1 = xc - w * 0.5f;
        float d2 = yc + h * 0.5f, d3 = xc + w * 0.5f;
        det[k][0] = d0; det[k][1] = d1; det[k][2] = d2; det[k][3] = d3;
        sbox[k] = make_float4(d0, d1, d2, d3);
        float kp[12] = {r1.x, r1.y, r1.z, r1.w,
                        r2.x, r2.y, r2.z, r2.w,
                        r3.x, r3.y, r3.z, r3.w};
        #pragma unroll
        for (int t = 0; t < 6; ++t) {
            det[k][4 + 2 * t] = kp[2 * t]     / 128.0f * aw + ax;
            det[k][5 + 2 * t] = kp[2 * t + 1] / 128.0f * ah + ay;
        }
    }
    __syncthreads();

    // ---- Phase 4: pairwise overlap bitmatrix (rows in registers) ----
    // lane owns rows lane, lane+64, lane+128; m{set}{word}.
    float4 sb0 = sbox[lane], sb1 = sbox[lane + 64], sb2 = sbox[lane + 128];
    float b00 = sb0.x, b01 = sb0.y, b02 = sb0.z, b03 = sb0.w;
    float b10 = sb1.x, b11 = sb1.y, b12 = sb1.z, b13 = sb1.w;
    float b20 = sb2.x, b21 = sb2.y, b22 = sb2.z, b23 = sb2.w;
    float a0 = (b02 - b00) * (b03 - b01);
    float a1 = (b12 - b10) * (b13 - b11);
    float a2 = (b22 - b20) * (b23 - b21);
    u64 m00 = 0, m01 = 0, m02 = 0;
    u64 m10 = 0, m11 = 0, m12 = 0;
    u64 m20 = 0, m21 = 0, m22 = 0;
    MATRIX_WORD(m00, m10, m20, 0)
    MATRIX_WORD(m01, m11, m21, 64)
    MATRIX_WORD(m02, m12, m22, 128)

    // ---- Phase 5: scalar cluster resolution (no vector work) ----
    u64 rem0 = (C >= 64)  ? ~0ull : ((C > 0)   ? ((1ull << C) - 1)         : 0ull);
    u64 rem1 = (C >= 128) ? ~0ull : ((C > 64)  ? ((1ull << (C - 64)) - 1)  : 0ull);
    u64 rem2 = (C >= 192) ? ~0ull : ((C > 128) ? ((1ull << (C - 128)) - 1) : 0ull);

    int step = 0;
    for (; step < MAXDET; ++step) {
        int i;
        if      (rem0) i = __builtin_ctzll(rem0);
        else if (rem1) i = __builtin_ctzll(rem1) + 64;
        else if (rem2) i = __builtin_ctzll(rem2) + 128;
        else break;
        int ol = i & 63, ow = i >> 6;
        u64 r0, r1, r2;
        if (ow == 0)      { r0 = rl64(m00, ol); r1 = rl64(m01, ol); r2 = rl64(m02, ol); }
        else if (ow == 1) { r0 = rl64(m10, ol); r1 = rl64(m11, ol); r2 = rl64(m12, ol); }
        else              { r0 = rl64(m20, ol); r1 = rl64(m21, ol); r2 = rl64(m22, ol); }
        u64 c0 = rem0 & r0, c1 = rem1 & r1, c2 = rem2 & r2;
        int n = (int)__popcll(c0) + (int)__popcll(c1) + (int)__popcll(c2);
        if (lane == 0) {
            pk[step]  = (u32)i | ((u32)n << 16);
            cl0[step] = c0; cl1[step] = c1; cl2[step] = c2;
        }
        rem0 &= ~c0; rem1 &= ~c1; rem2 &= ~c2;
    }
    const int nsteps = step;
    __syncthreads();

    // ---- Phase 6: parallel emission (steps independent) ----
    float* out_b = out   + (size_t)b * MAXDET * 17;
    float* flg_b = flags + (size_t)b * MAXDET;

    for (int s = lane; s < nsteps; s += 64) {
        u32 p = pk[s];
        int i = (int)(p & 0xffffu);
        int n = (int)(p >> 16);
        float* orow = out_b + s * 17;
        if (n <= 1) {
            #pragma unroll
            for (int c = 0; c < 17; ++c) orow[c] = det[i][c];
        } else {
            float tot = 0.0f, wc[16];
            #pragma unroll
            for (int c = 0; c < 16; ++c) wc[c] = 0.0f;
            ACCUM_WORD(cl0[s], 0)
            ACCUM_WORD(cl1[s], 64)
            ACCUM_WORD(cl2[s], 128)
            float safe = (tot > 0.0f) ? tot : 1.0f;
            #pragma unroll
            for (int c = 0; c < 16; ++c) orow[c] = wc[c] / safe;
            orow[16] = tot / (float)n;
        }
        flg_b[s] = 1.0f;
    }
    for (int t = nsteps * 17 + lane; t < MAXDET * 17; t += 64) out_b[t] = 0.0f;
    for (int t = nsteps + lane;      t < MAXDET;      t += 64) flg_b[t] = 0.0f;
}

// ---------------- fallback: C > 192 (statistically unreachable) ------------
__global__ __launch_bounds__(64, 1) void nms_fallback(
    const float* __restrict__ raw_box,
    const float* __restrict__ raw_score,
    const float* __restrict__ anchors,
    float* __restrict__ out,
    float* __restrict__ flags,
    const int* __restrict__ ws, int use_ws)
{
    const int b    = blockIdx.x;
    const int lane = threadIdx.x;
    if (use_ws && ws[b] <= CAP) return;   // cheap early-out

    __shared__ float det[NA][17];
    __shared__ int   cand_a[NA];

    int C = 0;
    const float* sc_base = raw_score + (size_t)b * NA;
    #pragma unroll
    for (int c = 0; c < NA / 64; ++c) {
        int a = c * 64 + lane;
        float x = sc_base[a];
        x = fminf(fmaxf(x, -100.0f), 100.0f);
        float s = 1.0f / (1.0f + expf(-x));
        bool v = (s >= 0.75f);
        u64 bal = __ballot(v);
        if (v) {
            int slot = C + (int)__popcll(bal & ((1ull << lane) - 1ull));
            cand_a[slot]  = a;
            det[slot][16] = s;
        }
        C += (int)__popcll(bal);
    }
    if (C <= CAP) return;   // fast kernel owns this block
    __syncthreads();

    for (int k = lane; k < C; k += 64) {
        int a = cand_a[k];
        const float4 an = ((const float4*)anchors)[a];
        const float4* rb = (const float4*)(raw_box + ((size_t)b * NA + a) * 16);
        float4 r0 = rb[0], r1 = rb[1], r2 = rb[2], r3 = rb[3];
        float ax = an.x, ay = an.y, aw = an.z, ah = an.w;
        float xc = r0.x / 128.0f * aw + ax;
        float yc = r0.y / 128.0f * ah + ay;
        float w  = r0.z / 128.0f * aw;
        float h  = r0.w / 128.0f * ah;
        det[k][0] = yc - h * 0.5f;
        det[k][1] = xc - w * 0.5f;
        det[k][2] = yc + h * 0.5f;
        det[k][3] = xc + w * 0.5f;
        float kp[12] = {r1.x, r1.y, r1.z, r1.w,
                        r2.x, r2.y, r2.z, r2.w,
                        r3.x, r3.y, r3.z, r3.w};
        #pragma unroll
        for (int t = 0; t < 6; ++t) {
            det[k][4 + 2 * t] = kp[2 * t]     / 128.0f * aw + ax;
            det[k][5 + 2 * t] = kp[2 * t + 1] / 128.0f * ah + ay;
        }
    }
    __syncthreads();

    const int nj = (C + 63) >> 6;
    unsigned int rem = 0;
    for (int j = 0; j < nj; ++j)
        if (lane + (j << 6) < C) rem |= (1u << j);

    float* out_b = out   + (size_t)b * MAXDET * 17;
    float* flg_b = flags + (size_t)b * MAXDET;

    int step = 0;
    for (; step < MAXDET; ++step) {
        u64 best = 0;
        for (int j = 0; j < nj; ++j) {
            if (rem & (1u << j)) {
                int k = lane + (j << 6);
                u64 key = ((u64)__float_as_uint(det[k][16]) << 10) |
                          (u64)(1023 - k);
                if (key > best) best = key;
            }
        }
        #pragma unroll
        for (int off = 32; off; off >>= 1) {
            u64 o = __shfl_xor(best, off);
            if (o > best) best = o;
        }
        if (best == 0) break;
        int idx = 1023 - (int)(best & 1023ull);

        float bx0 = det[idx][0], bx1 = det[idx][1];
        float bx2 = det[idx][2], bx3 = det[idx][3];
        float areaA = (bx2 - bx0) * (bx3 - bx1);

        unsigned int ov = 0;
        for (int j = 0; j < nj; ++j) {
            if (rem & (1u << j)) {
                int k = lane + (j << 6);
                float c0 = det[k][0], c1 = det[k][1];
                float c2 = det[k][2], c3 = det[k][3];
                float i0 = fmaxf(bx0, c0);
                float i1 = fmaxf(bx1, c1);
                float i2 = fminf(bx2, c2);
                float i3 = fminf(bx3, c3);
                float inter = (i2 - i0) * (i3 - i1);
                float areaB = (c2 - c0) * (c3 - c1);
                float q = inter / (areaA + areaB - inter);
                if (q > 0.3f) ov |= (1u << j);
            }
        }
        rem &= ~ov;

        int n = 0;
        for (int j = 0; j < nj; ++j)
            n += (int)__popcll(__ballot((ov >> j) & 1u));

        if (n <= 1) {
            if (lane < 17) out_b[step * 17 + lane] = det[idx][lane];
            if (lane == 17) flg_b[step] = 1.0f;
        } else {
            float tot = 0.0f, wc[16];
            #pragma unroll
            for (int c = 0; c < 16; ++c) wc[c] = 0.0f;
            for (int j = 0; j < nj; ++j) {
                if (ov & (1u << j)) {
                    int k = lane + (j << 6);
                    float s = det[k][16];
                    tot += s;
                    #pragma unroll
                    for (int c = 0; c < 16; ++c) wc[c] += det[k][c] * s;
                }
            }
            #pragma unroll
            for (int off = 32; off; off >>= 1) {
                tot += __shfl_xor(tot, off);
                #pragma unroll
                for (int c = 0; c < 16; ++c) wc[c] += __shfl_xor(wc[c], off);
            }
            if (lane == 0) {
                float safe = (tot > 0.0f) ? tot : 1.0f;
                #pragma unroll
                for (int c = 0; c < 16; ++c) out_b[step * 17 + c] = wc[c] / safe;
                out_b[step * 17 + 16] = tot / (float)n;
                flg_b[step] = 1.0f;
            }
        }
    }

    for (int t = step * 17 + lane; t < MAXDET * 17; t += 64) out_b[t] = 0.0f;
    for (int t = step + lane;      t < MAXDET;      t += 64) flg_b[t] = 0.0f;
}

extern "C" void kernel_launch(void* const* d_in, const int* in_sizes, int n_in,
                              void* d_out, int out_size, void* d_ws, size_t ws_size,
                              hipStream_t stream) {
    const float* raw_box   = (const float*)d_in[0];
    const float* raw_score = (const float*)d_in[1];
    const float* anchors   = (const float*)d_in[2];
    float* out   = (float*)d_out;
    float* flags = out + (size_t)NBATCH * MAXDET * 17;
    int use_ws = (ws_size >= NBATCH * sizeof(int)) ? 1 : 0;
    nms_fast    <<<NBATCH, 64, 0, stream>>>(raw_box, raw_score, anchors, out, flags,
                                            (int*)d_ws, use_ws);
    nms_fallback<<<NBATCH, 64, 0, stream>>>(raw_box, raw_score, anchors, out, flags,
                                            (const int*)d_ws, use_ws);
}

// Round 4
// 51.630 us; speedup vs baseline: 3.3125x; 1.3083x over previous
//
#include <hip/hip_runtime.h>
#include <math.h>

#pragma clang fp contract(off)

#define NA      896
#define MAXDET  256
#define NBATCH  512
#define CAP     192
#define NCHUNK  14

typedef unsigned long long u64;
typedef unsigned int u32;

__device__ __forceinline__ u64 rl64(u64 v, int l) {
    u32 lo = __builtin_amdgcn_readlane((u32)v, l);
    u32 hi = __builtin_amdgcn_readlane((u32)(v >> 32), l);
    return ((u64)hi << 32) | (u64)lo;
}

#define ACCUM_WORD(MASK, BASE)                                         \
    {                                                                  \
        u64 m_ = (MASK);                                               \
        while (m_) {                                                   \
            int k_ = __builtin_ctzll(m_) + (BASE);                     \
            m_ &= m_ - 1;                                              \
            float sc_ = det[k_][16];                                   \
            tot += sc_;                                                \
            _Pragma("unroll")                                          \
            for (int c = 0; c < 16; ++c) wc[c] += det[k_][c] * sc_;    \
        }                                                              \
    }

// ---------------- fast path: C <= 192, one batch per 4-wave block ----------
__global__ __launch_bounds__(256, 1) void nms_fast(
    const float* __restrict__ raw_box,
    const float* __restrict__ raw_score,
    const float* __restrict__ anchors,
    float* __restrict__ out,
    float* __restrict__ flags,
    int* __restrict__ ws, int use_ws)
{
    __shared__ float  det[CAP][17];
    __shared__ float4 sbox[CAP];
    __shared__ u64    keys[CAP];
    __shared__ int    slot_a[CAP];
    __shared__ float  slot_s[CAP];
    __shared__ int    srt_a[CAP];
    __shared__ u64    mat0[CAP], mat1[CAP], mat2[CAP];
    __shared__ u64    cl0[MAXDET], cl1[MAXDET], cl2[MAXDET];
    __shared__ u32    pk[MAXDET];
    __shared__ int    cnt[NCHUNK];
    __shared__ int    nsteps_sh;

    const int b    = blockIdx.x;
    const int tid  = threadIdx.x;
    const int lane = tid & 63;
    const int wv   = tid >> 6;

    const float* sc_base = raw_score + (size_t)b * NA;
    float* out_b = out   + (size_t)b * MAXDET * 17;
    float* flg_b = flags + (size_t)b * MAXDET;

    // ---- Phase 1a: scores + per-chunk ballots (wave wv owns chunks wv+4k) ----
    float s_r[4]; u64 bal_r[4]; bool v_r[4];
    #pragma unroll
    for (int it = 0; it < 4; ++it) {
        int c = wv + it * 4;
        s_r[it] = 0.0f; bal_r[it] = 0ull; v_r[it] = false;
        if (c < NCHUNK) {
            float x = sc_base[c * 64 + lane];
            x = fminf(fmaxf(x, -100.0f), 100.0f);
            float s = 1.0f / (1.0f + expf(-x));
            bool v = (s >= 0.75f);
            u64 bal = __ballot(v);
            s_r[it] = s; bal_r[it] = bal; v_r[it] = v;
            if (lane == 0) cnt[c] = (int)__popcll(bal);
        }
    }
    __syncthreads();

    // ---- Phase 1b: prefix (register-resident, static indexing) + scatter ----
    int cn[NCHUNK];
    #pragma unroll
    for (int j = 0; j < NCHUNK; ++j) cn[j] = cnt[j];
    int C = 0;
    #pragma unroll
    for (int j = 0; j < NCHUNK; ++j) C += cn[j];
    if (use_ws && tid == 0) ws[b] = C;
    if (C > CAP) return;   // uniform across block; fallback kernel owns it
    #pragma unroll
    for (int it = 0; it < 4; ++it) {
        int c = wv + it * 4;
        if (c < NCHUNK && v_r[it]) {
            int base = 0;
            #pragma unroll
            for (int j = 0; j < NCHUNK; ++j) base += (j < c) ? cn[j] : 0;
            int slot = base + (int)__popcll(bal_r[it] & ((1ull << lane) - 1ull));
            keys[slot]   = ((u64)__float_as_uint(s_r[it]) << 8) | (u64)(255 - slot);
            slot_a[slot] = c * 64 + lane;
            slot_s[slot] = s_r[it];
        }
    }
    __syncthreads();

    // ---- Phase 2: rank-by-count sort (thread t owns slot t; keys unique) ----
    {
        u64 myk = (tid < C) ? keys[tid] : 0ull;
        int q = 0;
        #pragma unroll 4
        for (int i = 0; i < C; ++i) q += (keys[i] > myk) ? 1 : 0;
        if (tid < C) { srt_a[q] = slot_a[tid]; det[q][16] = slot_s[tid]; }
    }
    __syncthreads();

    // ---- Phase 3: decode (one sorted row per thread) ----
    if (tid < C) {
        int a = srt_a[tid];
        const float4 an = ((const float4*)anchors)[a];
        const float4* rb = (const float4*)(raw_box + ((size_t)b * NA + a) * 16);
        float4 r0 = rb[0], r1 = rb[1], r2 = rb[2], r3 = rb[3];
        float ax = an.x, ay = an.y, aw = an.z, ah = an.w;
        float xc = r0.x / 128.0f * aw + ax;
        float yc = r0.y / 128.0f * ah + ay;
        float w  = r0.z / 128.0f * aw;
        float h  = r0.w / 128.0f * ah;
        float d0 = yc - h * 0.5f, d1 = xc - w * 0.5f;
        float d2 = yc + h * 0.5f, d3 = xc + w * 0.5f;
        det[tid][0] = d0; det[tid][1] = d1; det[tid][2] = d2; det[tid][3] = d3;
        sbox[tid] = make_float4(d0, d1, d2, d3);
        float kp[12] = {r1.x, r1.y, r1.z, r1.w,
                        r2.x, r2.y, r2.z, r2.w,
                        r3.x, r3.y, r3.z, r3.w};
        #pragma unroll
        for (int t = 0; t < 6; ++t) {
            det[tid][4 + 2 * t] = kp[2 * t]     / 128.0f * aw + ax;
            det[tid][5 + 2 * t] = kp[2 * t + 1] / 128.0f * ah + ay;
        }
    }
    __syncthreads();

    // ---- Phase 4: overlap bitmatrix, one row per thread ----
    if (tid < C) {
        float4 sb = sbox[tid];
        float bx = sb.x, by = sb.y, bz = sb.z, bw = sb.w;
        float ar = (bz - bx) * (bw - by);   // area of the OWN (picked) row
        u64 mw0 = 0, mw1 = 0, mw2 = 0;
        #pragma unroll
        for (int w_ = 0; w_ < 3; ++w_) {
            int base = w_ * 64;
            int ke = C - base; if (ke > 64) ke = 64;
            u64 mm = 0, bit = 1ull;
            #pragma unroll 4
            for (int k = 0; k < ke; ++k, bit <<= 1) {
                float4 bk = sbox[base + k];
                float ak = (bk.z - bk.x) * (bk.w - bk.y);
                float i0 = fmaxf(bx, bk.x), i1 = fmaxf(by, bk.y);
                float i2 = fminf(bz, bk.z), i3 = fminf(bw, bk.w);
                float inter = (i2 - i0) * (i3 - i1);
                float qq = inter / (ar + ak - inter);  // NaN -> no bit
                if (qq > 0.3f) mm |= bit;
            }
            if (w_ == 0) mw0 = mm; else if (w_ == 1) mw1 = mm; else mw2 = mm;
        }
        mat0[tid] = mw0; mat1[tid] = mw1; mat2[tid] = mw2;
    }
    __syncthreads();

    // ---- Phase 5: wave 0 resolves clusters; waves 1-3 zero-fill output ----
    if (wv == 0) {
        u64 m00 = mat0[lane],       m01 = mat1[lane],       m02 = mat2[lane];
        u64 m10 = mat0[lane + 64],  m11 = mat1[lane + 64],  m12 = mat2[lane + 64];
        u64 m20 = mat0[lane + 128], m21 = mat1[lane + 128], m22 = mat2[lane + 128];
        u64 rem0 = (C >= 64)  ? ~0ull : ((C > 0)   ? ((1ull << C) - 1)         : 0ull);
        u64 rem1 = (C >= 128) ? ~0ull : ((C > 64)  ? ((1ull << (C - 64)) - 1)  : 0ull);
        u64 rem2 = (C >= 192) ? ~0ull : ((C > 128) ? ((1ull << (C - 128)) - 1) : 0ull);

        int step = 0;
        for (; step < MAXDET; ++step) {
            int i;
            if      (rem0) i = __builtin_ctzll(rem0);
            else if (rem1) i = 64 + __builtin_ctzll(rem1);
            else if (rem2) i = 128 + __builtin_ctzll(rem2);
            else break;
            int ol = i & 63, ow = i >> 6;
            u64 r0, r1, r2;
            if (ow == 0)      { r0 = rl64(m00, ol); r1 = rl64(m01, ol); r2 = rl64(m02, ol); }
            else if (ow == 1) { r0 = rl64(m10, ol); r1 = rl64(m11, ol); r2 = rl64(m12, ol); }
            else              { r0 = rl64(m20, ol); r1 = rl64(m21, ol); r2 = rl64(m22, ol); }
            u64 c0 = rem0 & r0, c1 = rem1 & r1, c2 = rem2 & r2;
            int n = (int)__popcll(c0) + (int)__popcll(c1) + (int)__popcll(c2);
            if (lane == 0) {
                pk[step]  = (u32)i | ((u32)n << 16);
                cl0[step] = c0; cl1[step] = c1; cl2[step] = c2;
            }
            rem0 &= ~c0; rem1 &= ~c1; rem2 &= ~c2;
        }
        if (lane == 0) nsteps_sh = step;
    } else {
        // overlapped with resolution; emission later overwrites rows < nsteps
        for (int t = tid - 64; t < MAXDET * 17; t += 192) out_b[t] = 0.0f;
        for (int t = tid - 64; t < MAXDET;      t += 192) flg_b[t] = 0.0f;
    }
    __syncthreads();
    const int nsteps = nsteps_sh;

    // ---- Phase 6: parallel emission, one step per thread ----
    if (tid < nsteps) {
        u32 p = pk[tid];
        int i = (int)(p & 0xffffu);
        int n = (int)(p >> 16);
        float* orow = out_b + tid * 17;
        if (n <= 1) {
            #pragma unroll
            for (int c = 0; c < 17; ++c) orow[c] = det[i][c];
        } else {
            float tot = 0.0f, wc[16];
            #pragma unroll
            for (int c = 0; c < 16; ++c) wc[c] = 0.0f;
            ACCUM_WORD(cl0[tid], 0)
            ACCUM_WORD(cl1[tid], 64)
            ACCUM_WORD(cl2[tid], 128)
            float safe = (tot > 0.0f) ? tot : 1.0f;
            #pragma unroll
            for (int c = 0; c < 16; ++c) orow[c] = wc[c] / safe;
            orow[16] = tot / (float)n;
        }
        flg_b[tid] = 1.0f;
    }
}

// ---------------- fallback: C > 192 (statistically unreachable) ------------
__global__ __launch_bounds__(64, 1) void nms_fallback(
    const float* __restrict__ raw_box,
    const float* __restrict__ raw_score,
    const float* __restrict__ anchors,
    float* __restrict__ out,
    float* __restrict__ flags,
    const int* __restrict__ ws, int use_ws)
{
    const int b    = blockIdx.x;
    const int lane = threadIdx.x;
    if (use_ws && ws[b] <= CAP) return;   // cheap early-out

    __shared__ float det[NA][17];
    __shared__ int   cand_a[NA];

    int C = 0;
    const float* sc_base = raw_score + (size_t)b * NA;
    #pragma unroll
    for (int c = 0; c < NA / 64; ++c) {
        int a = c * 64 + lane;
        float x = sc_base[a];
        x = fminf(fmaxf(x, -100.0f), 100.0f);
        float s = 1.0f / (1.0f + expf(-x));
        bool v = (s >= 0.75f);
        u64 bal = __ballot(v);
        if (v) {
            int slot = C + (int)__popcll(bal & ((1ull << lane) - 1ull));
            cand_a[slot]  = a;
            det[slot][16] = s;
        }
        C += (int)__popcll(bal);
    }
    if (C <= CAP) return;   // fast kernel owns this block
    __syncthreads();

    for (int k = lane; k < C; k += 64) {
        int a = cand_a[k];
        const float4 an = ((const float4*)anchors)[a];
        const float4* rb = (const float4*)(raw_box + ((size_t)b * NA + a) * 16);
        float4 r0 = rb[0], r1 = rb[1], r2 = rb[2], r3 = rb[3];
        float ax = an.x, ay = an.y, aw = an.z, ah = an.w;
        float xc = r0.x / 128.0f * aw + ax;
        float yc = r0.y / 128.0f * ah + ay;
        float w  = r0.z / 128.0f * aw;
        float h  = r0.w / 128.0f * ah;
        det[k][0] = yc - h * 0.5f;
        det[k][1] = xc - w * 0.5f;
        det[k][2] = yc + h * 0.5f;
        det[k][3] = xc + w * 0.5f;
        float kp[12] = {r1.x, r1.y, r1.z, r1.w,
                        r2.x, r2.y, r2.z, r2.w,
                        r3.x, r3.y, r3.z, r3.w};
        #pragma unroll
        for (int t = 0; t < 6; ++t) {
            det[k][4 + 2 * t] = kp[2 * t]     / 128.0f * aw + ax;
            det[k][5 + 2 * t] = kp[2 * t + 1] / 128.0f * ah + ay;
        }
    }
    __syncthreads();

    const int nj = (C + 63) >> 6;
    unsigned int rem = 0;
    for (int j = 0; j < nj; ++j)
        if (lane + (j << 6) < C) rem |= (1u << j);

    float* out_b = out   + (size_t)b * MAXDET * 17;
    float* flg_b = flags + (size_t)b * MAXDET;

    int step = 0;
    for (; step < MAXDET; ++step) {
        u64 best = 0;
        for (int j = 0; j < nj; ++j) {
            if (rem & (1u << j)) {
                int k = lane + (j << 6);
                u64 key = ((u64)__float_as_uint(det[k][16]) << 10) |
                          (u64)(1023 - k);
                if (key > best) best = key;
            }
        }
        #pragma unroll
        for (int off = 32; off; off >>= 1) {
            u64 o = __shfl_xor(best, off);
            if (o > best) best = o;
        }
        if (best == 0) break;
        int idx = 1023 - (int)(best & 1023ull);

        float bx0 = det[idx][0], bx1 = det[idx][1];
        float bx2 = det[idx][2], bx3 = det[idx][3];
        float areaA = (bx2 - bx0) * (bx3 - bx1);

        unsigned int ov = 0;
        for (int j = 0; j < nj; ++j) {
            if (rem & (1u << j)) {
                int k = lane + (j << 6);
                float c0 = det[k][0], c1 = det[k][1];
                float c2 = det[k][2], c3 = det[k][3];
                float i0 = fmaxf(bx0, c0);
                float i1 = fmaxf(bx1, c1);
                float i2 = fminf(bx2, c2);
                float i3 = fminf(bx3, c3);
                float inter = (i2 - i0) * (i3 - i1);
                float areaB = (c2 - c0) * (c3 - c1);
                float q = inter / (areaA + areaB - inter);
                if (q > 0.3f) ov |= (1u << j);
            }
        }
        rem &= ~ov;

        int n = 0;
        for (int j = 0; j < nj; ++j)
            n += (int)__popcll(__ballot((ov >> j) & 1u));

        if (n <= 1) {
            if (lane < 17) out_b[step * 17 + lane] = det[idx][lane];
            if (lane == 17) flg_b[step] = 1.0f;
        } else {
            float tot = 0.0f, wc[16];
            #pragma unroll
            for (int c = 0; c < 16; ++c) wc[c] = 0.0f;
            for (int j = 0; j < nj; ++j) {
                if (ov & (1u << j)) {
                    int k = lane + (j << 6);
                    float s = det[k][16];
                    tot += s;
                    #pragma unroll
                    for (int c = 0; c < 16; ++c) wc[c] += det[k][c] * s;
                }
            }
            #pragma unroll
            for (int off = 32; off; off >>= 1) {
                tot += __shfl_xor(tot, off);
                #pragma unroll
                for (int c = 0; c < 16; ++c) wc[c] += __shfl_xor(wc[c], off);
            }
            if (lane == 0) {
                float safe = (tot > 0.0f) ? tot : 1.0f;
                #pragma unroll
                for (int c = 0; c < 16; ++c) out_b[step * 17 + c] = wc[c] / safe;
                out_b[step * 17 + 16] = tot / (float)n;
                flg_b[step] = 1.0f;
            }
        }
    }

    for (int t = step * 17 + lane; t < MAXDET * 17; t += 64) out_b[t] = 0.0f;
    for (int t = step + lane;      t < MAXDET;      t += 64) flg_b[t] = 0.0f;
}

extern "C" void kernel_launch(void* const* d_in, const int* in_sizes, int n_in,
                              void* d_out, int out_size, void* d_ws, size_t ws_size,
                              hipStream_t stream) {
    const float* raw_box   = (const float*)d_in[0];
    const float* raw_score = (const float*)d_in[1];
    const float* anchors   = (const float*)d_in[2];
    float* out   = (float*)d_out;
    float* flags = out + (size_t)NBATCH * MAXDET * 17;
    int use_ws = (ws_size >= NBATCH * sizeof(int)) ? 1 : 0;
    nms_fast    <<<NBATCH, 256, 0, stream>>>(raw_box, raw_score, anchors, out, flags,
                                             (int*)d_ws, use_ws);
    nms_fallback<<<NBATCH, 64, 0, stream>>>(raw_box, raw_score, anchors, out, flags,
                                            (const int*)d_ws, use_ws);
}